// Round 7
// baseline (560.684 us; speedup 1.0000x reference)
//
#include <hip/hip_runtime.h>
#include <math.h>

typedef unsigned short u16;
typedef unsigned int u32;
typedef __attribute__((ext_vector_type(8))) short short8; // 8 x bf16 (4 VGPRs)
typedef __attribute__((ext_vector_type(4))) float f32x4;

__device__ __forceinline__ float b2f(u16 u) {
    u32 x = ((u32)u) << 16;
    return __builtin_bit_cast(float, x);
}
__device__ __forceinline__ u16 f2b(float f) { // RNE bf16
    u32 x = __builtin_bit_cast(u32, f);
    u32 r = x + 0x7fffu + ((x >> 16) & 1u);
    return (u16)(r >> 16);
}
__device__ __forceinline__ void split_hl(float x, u16& h, u16& l) {
    u16 hb = f2b(x);
    h = hb;
    l = f2b(x - b2f(hb));
}
// fast gelu_new: tanh(y) = 1 - 2/(1+e^{2y}) via __expf (inf-safe)
__device__ __forceinline__ float gelu_new_f(float x) {
    const float c = 0.7978845608028654f;
    float y = c * (x + 0.044715f * x * x * x);
    float t = 1.0f - 2.0f / (1.0f + __expf(2.0f * y));
    return 0.5f * x * (1.0f + t);
}
// breadcrumb: NaN OR inf -> stage-distinctive magnitude
__device__ __forceinline__ float scrub(float v, float s) {
    return (fabsf(v) < 1e25f) ? v : s;
}
// async global->LDS, 16B per lane; LDS dest = wave-uniform base + lane*16
__device__ __forceinline__ void gld16(const void* g, void* l) {
    __builtin_amdgcn_global_load_lds((const __attribute__((address_space(1))) u32*)g,
                                     (__attribute__((address_space(3))) u32*)l,
                                     16, 0, 0);
}
__device__ __forceinline__ short8 ldf(const u16* p) { return *(const short8*)p; }

// -------- transpose+convert: src fp32 [R][C] -> dst bf16 [C][R] ------------
__global__ __launch_bounds__(256) void transpose_cvt(const float* __restrict__ src,
                                                     u16* __restrict__ dst, int R, int C) {
    __shared__ u16 t[32][33];
    int c0 = blockIdx.x * 32, r0 = blockIdx.y * 32;
    int x = threadIdx.x & 31, y = threadIdx.x >> 5; // 32 x 8
#pragma unroll
    for (int i = 0; i < 32; i += 8)
        t[y + i][x] = f2b(src[(size_t)(r0 + y + i) * C + c0 + x]);
    __syncthreads();
#pragma unroll
    for (int i = 0; i < 32; i += 8)
        dst[(size_t)(c0 + y + i) * R + r0 + x] = t[x][y + i];
}

// -------- T5 rel-pos bias table + additive mask (fp32 inputs) --------------
// tab and mask_add are pre-scaled by log2(e); mask_add also folds the softmax
// fixed shift (-20). Attention computes p = exp2(z' + b' + m') == e^(z+b+m-20).
__global__ void bias_table_kernel(const float* __restrict__ rel_bias,
                                  const float* __restrict__ mask,
                                  float* __restrict__ tab,
                                  float* __restrict__ mask_add) {
    const float LOG2E = 1.4426950408889634f;
    int idx = blockIdx.x * 256 + threadIdx.x; // 0..4095
    if (idx < 4095) {
        int rel = idx - 2047;
        int ret = rel > 0 ? 16 : 0;
        int n = rel < 0 ? -rel : rel;
        int bucket;
        if (n < 8) {
            bucket = ret + n;
        } else {
            int v = 8 + (int)(logf((float)n * 0.125f) * (8.0f / 2.7725887222397811f));
            v = v < 15 ? v : 15;
            bucket = ret + v;
        }
#pragma unroll
        for (int h = 0; h < 16; h++)
            tab[h * 4096 + idx] = rel_bias[bucket * 16 + h] * LOG2E;
    }
    if (idx < 4096)
        mask_add[idx] = ((1.0f - mask[idx]) * -10000.0f - 20.0f) * LOG2E;
}

// -------- RMSNorm: fp32 in -> bf16 ----------------------------------------
__global__ __launch_bounds__(256) void rmsnorm_k(const float* __restrict__ X,
                                                 const float* __restrict__ W,
                                                 u16* __restrict__ Y) {
    __shared__ float red[4];
    int row = blockIdx.x, tid = threadIdx.x;
    const float* xr = X + (size_t)row * 1024;
    float4 x = *(const float4*)(xr + tid * 4);
    float ss = x.x * x.x + x.y * x.y + x.z * x.z + x.w * x.w;
#pragma unroll
    for (int off = 32; off; off >>= 1) ss += __shfl_xor(ss, off, 64);
    if ((tid & 63) == 0) red[tid >> 6] = ss;
    __syncthreads();
    float tot = red[0] + red[1] + red[2] + red[3];
    float s = rsqrtf(tot * (1.0f / 1024.0f) + 1e-6f);
    float4 w4 = *(const float4*)(W + tid * 4);
    float y0 = scrub(x.x * s * w4.x, 1e3f);
    float y1 = scrub(x.y * s * w4.y, 1e3f);
    float y2 = scrub(x.z * s * w4.z, 1e3f);
    float y3 = scrub(x.w * s * w4.w, 1e3f);
    uint2 o;
    o.x = (u32)f2b(y0) | ((u32)f2b(y1) << 16);
    o.y = (u32)f2b(y2) | ((u32)f2b(y3) << 16);
    *(uint2*)(Y + (size_t)row * 1024 + tid * 4) = o;
}

// ===== BK=64 XOR-swizzled staging ==========================================
// LDS tile: rows x 64 cols bf16, row stride 128 B. 16B block b of row r holds
// global col-block b^(r&7) -> conflict-free ds_read_b128 fragment loads.

// -------- merged QKV GEMM (single-plane A), K=1024, N=3072 -----------------
// epilogue: Q -> fp32 qb; K -> bf16 hi/lo planes; V -> transposed bf16 vT
__global__ __launch_bounds__(256) void gemm_qkv(const u16* __restrict__ A,
                                                const u16* __restrict__ Bt,
                                                float* __restrict__ qb,
                                                u16* __restrict__ Kh,
                                                u16* __restrict__ Kl,
                                                u16* __restrict__ vT) {
    const int K = 1024;
    __shared__ __align__(16) u16 As[128 * 64];
    __shared__ __align__(16) u16 Bs[128 * 64];
    int tid = threadIdx.x;
    int wave = tid >> 6, lane = tid & 63, quad = lane >> 4, l15 = lane & 15;
    int bm = blockIdx.y * 128, bn = blockIdx.x * 128;
    int wm = (wave >> 1) * 64, wn = (wave & 1) * 64;
    f32x4 acc[4][4] = {};
    int lr = lane >> 3, cb = (lane & 7) ^ (lr & 7);
    const u16* ga = A + (size_t)(bm + wave * 32 + lr) * K + cb * 8;
    const u16* gb = Bt + (size_t)(bn + wave * 32 + lr) * K + cb * 8;
    u16* la = As + wave * 2048;
    u16* lb = Bs + wave * 2048;
    int swz = l15 & 7;
    for (int k0 = 0; k0 < K; k0 += 64) {
        __syncthreads();
#pragma unroll
        for (int g = 0; g < 4; g++) {
            gld16(ga + k0 + (size_t)(g * 8) * K, la + g * 512);
            gld16(gb + k0 + (size_t)(g * 8) * K, lb + g * 512);
        }
        __syncthreads();
#pragma unroll
        for (int s = 0; s < 2; s++) {
            int kb = ((s * 4 + quad) ^ swz) * 8;
            short8 af[4], bf[4];
#pragma unroll
            for (int i = 0; i < 4; i++)
                af[i] = ldf(As + (wm + i * 16 + l15) * 64 + kb);
#pragma unroll
            for (int j = 0; j < 4; j++)
                bf[j] = ldf(Bs + (wn + j * 16 + l15) * 64 + kb);
#pragma unroll
            for (int i = 0; i < 4; i++)
#pragma unroll
                for (int j = 0; j < 4; j++)
                    acc[i][j] = __builtin_amdgcn_mfma_f32_16x16x32_bf16(af[i], bf[j], acc[i][j], 0, 0, 0);
        }
    }
    if (bn < 1024) {            // Q -> fp32
#pragma unroll
        for (int i = 0; i < 4; i++)
#pragma unroll
            for (int j = 0; j < 4; j++) {
                int col = bn + wn + j * 16 + l15;
#pragma unroll
                for (int r = 0; r < 4; r++) {
                    int row = bm + wm + i * 16 + quad * 4 + r;
                    qb[(size_t)row * 1024 + col] = scrub(acc[i][j][r], 1e4f);
                }
            }
    } else if (bn < 2048) {     // K -> hi/lo bf16 planes
#pragma unroll
        for (int i = 0; i < 4; i++)
#pragma unroll
            for (int j = 0; j < 4; j++) {
                int col = bn - 1024 + wn + j * 16 + l15;
#pragma unroll
                for (int r = 0; r < 4; r++) {
                    int row = bm + wm + i * 16 + quad * 4 + r;
                    u16 hh, ll;
                    split_hl(scrub(acc[i][j][r], 1e4f), hh, ll);
                    Kh[(size_t)row * 1024 + col] = hh;
                    Kl[(size_t)row * 1024 + col] = ll;
                }
            }
    } else {                    // V -> transposed bf16 vT[d][B*S]
#pragma unroll
        for (int i = 0; i < 4; i++)
#pragma unroll
            for (int j = 0; j < 4; j++) {
                int col = bn - 2048 + wn + j * 16 + l15;
                int row0 = bm + wm + i * 16 + quad * 4;
                ushort4 p;
                p.x = f2b(scrub(acc[i][j][0], 1e4f));
                p.y = f2b(scrub(acc[i][j][1], 1e4f));
                p.z = f2b(scrub(acc[i][j][2], 1e4f));
                p.w = f2b(scrub(acc[i][j][3], 1e4f));
                *(ushort4*)(vT + (size_t)col * 4096 + row0) = p;
            }
    }
}

// -------- GEMM: C fp32 = A bf16 [M,K] @ Bt [N,K]^T + Res fp32, BK=64 -------
__global__ __launch_bounds__(256) void gemm_bt_res(const u16* __restrict__ A,
                                                   const u16* __restrict__ Bt,
                                                   float* __restrict__ C,
                                                   const float* __restrict__ Res,
                                                   int M, int N, int K, float sval) {
    __shared__ __align__(16) u16 As[128 * 64];
    __shared__ __align__(16) u16 Bs[128 * 64];
    int tid = threadIdx.x;
    int wave = tid >> 6, lane = tid & 63, quad = lane >> 4, l15 = lane & 15;
    int bm = blockIdx.y * 128, bn = blockIdx.x * 128;
    int wm = (wave >> 1) * 64, wn = (wave & 1) * 64;
    f32x4 acc[4][4] = {};
    int lr = lane >> 3, cb = (lane & 7) ^ (lr & 7);
    const u16* ga = A + (size_t)(bm + wave * 32 + lr) * K + cb * 8;
    const u16* gb = Bt + (size_t)(bn + wave * 32 + lr) * K + cb * 8;
    u16* la = As + wave * 2048;
    u16* lb = Bs + wave * 2048;
    int swz = l15 & 7;
    for (int k0 = 0; k0 < K; k0 += 64) {
        __syncthreads();
#pragma unroll
        for (int g = 0; g < 4; g++) {
            gld16(ga + k0 + (size_t)(g * 8) * K, la + g * 512);
            gld16(gb + k0 + (size_t)(g * 8) * K, lb + g * 512);
        }
        __syncthreads();
#pragma unroll
        for (int s = 0; s < 2; s++) {
            int kb = ((s * 4 + quad) ^ swz) * 8;
            short8 af[4], bf[4];
#pragma unroll
            for (int i = 0; i < 4; i++)
                af[i] = ldf(As + (wm + i * 16 + l15) * 64 + kb);
#pragma unroll
            for (int j = 0; j < 4; j++)
                bf[j] = ldf(Bs + (wn + j * 16 + l15) * 64 + kb);
#pragma unroll
            for (int i = 0; i < 4; i++)
#pragma unroll
                for (int j = 0; j < 4; j++)
                    acc[i][j] = __builtin_amdgcn_mfma_f32_16x16x32_bf16(af[i], bf[j], acc[i][j], 0, 0, 0);
        }
    }
#pragma unroll
    for (int i = 0; i < 4; i++)
#pragma unroll
        for (int j = 0; j < 4; j++) {
            int col = bn + wn + j * 16 + l15;
#pragma unroll
            for (int r = 0; r < 4; r++) {
                int row = bm + wm + i * 16 + quad * 4 + r;
                float v = acc[i][j][r] + Res[(size_t)row * N + col];
                C[(size_t)row * N + col] = scrub(v, sval);
            }
        }
}

// -------- Dual GEMM + gated GELU: C = gelu(A@B1t^T) * (A@B2t^T), BK=64 -----
__global__ __launch_bounds__(256) void gemm_dual_gelu(const u16* __restrict__ A,
                                                      const u16* __restrict__ B1t,
                                                      const u16* __restrict__ B2t,
                                                      u16* __restrict__ C,
                                                      int M, int N, int K) {
    __shared__ __align__(16) u16 As[128 * 64];
    __shared__ __align__(16) u16 B1s[128 * 64];
    __shared__ __align__(16) u16 B2s[128 * 64];
    int tid = threadIdx.x;
    int wave = tid >> 6, lane = tid & 63, quad = lane >> 4, l15 = lane & 15;
    int bm = blockIdx.y * 128, bn = blockIdx.x * 128;
    int wm = (wave >> 1) * 64, wn = (wave & 1) * 64;
    f32x4 acc1[4][4] = {};
    f32x4 acc2[4][4] = {};
    int lr = lane >> 3, cb = (lane & 7) ^ (lr & 7);
    const u16* ga = A + (size_t)(bm + wave * 32 + lr) * K + cb * 8;
    const u16* g1 = B1t + (size_t)(bn + wave * 32 + lr) * K + cb * 8;
    const u16* g2 = B2t + (size_t)(bn + wave * 32 + lr) * K + cb * 8;
    u16* la = As + wave * 2048;
    u16* l1 = B1s + wave * 2048;
    u16* l2 = B2s + wave * 2048;
    int swz = l15 & 7;
    for (int k0 = 0; k0 < K; k0 += 64) {
        __syncthreads();
#pragma unroll
        for (int g = 0; g < 4; g++) {
            gld16(ga + k0 + (size_t)(g * 8) * K, la + g * 512);
            gld16(g1 + k0 + (size_t)(g * 8) * K, l1 + g * 512);
            gld16(g2 + k0 + (size_t)(g * 8) * K, l2 + g * 512);
        }
        __syncthreads();
#pragma unroll
        for (int s = 0; s < 2; s++) {
            int kb = ((s * 4 + quad) ^ swz) * 8;
            short8 af[4], b1f[4], b2f_[4];
#pragma unroll
            for (int i = 0; i < 4; i++)
                af[i] = ldf(As + (wm + i * 16 + l15) * 64 + kb);
#pragma unroll
            for (int j = 0; j < 4; j++) {
                b1f[j] = ldf(B1s + (wn + j * 16 + l15) * 64 + kb);
                b2f_[j] = ldf(B2s + (wn + j * 16 + l15) * 64 + kb);
            }
#pragma unroll
            for (int i = 0; i < 4; i++)
#pragma unroll
                for (int j = 0; j < 4; j++) {
                    acc1[i][j] = __builtin_amdgcn_mfma_f32_16x16x32_bf16(af[i], b1f[j], acc1[i][j], 0, 0, 0);
                    acc2[i][j] = __builtin_amdgcn_mfma_f32_16x16x32_bf16(af[i], b2f_[j], acc2[i][j], 0, 0, 0);
                }
        }
    }
#pragma unroll
    for (int i = 0; i < 4; i++)
#pragma unroll
        for (int j = 0; j < 4; j++) {
            int col = bn + wn + j * 16 + l15;
#pragma unroll
            for (int r = 0; r < 4; r++) {
                int row = bm + wm + i * 16 + quad * 4 + r;
                float v = gelu_new_f(acc1[i][j][r]) * acc2[i][j][r];
                C[(size_t)row * N + col] = f2b(scrub(v, 1e10f));
            }
        }
}

// -------- MFMA flash attention v3 ------------------------------------------
// grid (S/64, H, B), 256 thr. KT=64 k-tiles, Q A-frags direct from global
// (no Q LDS), exp2 softmax (Q/bias/mask pre-scaled by log2e), MFMA row-sum
// denominator, XOR-swizzled K/V staging.
__global__ __launch_bounds__(256) void attn_kernel(const float* __restrict__ Qb,
                                                   const u16* __restrict__ Kh,
                                                   const u16* __restrict__ Kl,
                                                   const u16* __restrict__ vT,
                                                   const float* __restrict__ bias_tab,
                                                   const float* __restrict__ mask_add,
                                                   u16* __restrict__ Ctx) {
    __shared__ __align__(16) u16 Khs[64 * 64];  // swizzled: blk ^= (row&7)
    __shared__ __align__(16) u16 Kls[64 * 64];
    __shared__ __align__(16) u16 Vs[64 * 64];   // [d][kv], swizzled
    __shared__ __align__(16) u16 Pss[4 * 16 * 72];
    const float LOG2E = 1.4426950408889634f;
    int tid = threadIdx.x, wave = tid >> 6, lane = tid & 63;
    int quad = lane >> 4, l15 = lane & 15;
    int h = blockIdx.y, b = blockIdx.z;
    int q0 = blockIdx.x * 64;
    // Q A-fragment direct load: lane owns q-row (wave*16+l15), k = half*32+quad*8+j
    short8 qh0, qh1, ql0, ql1;
    {
        const float* Qg = Qb + (size_t)(b * 2048 + q0 + wave * 16 + l15) * 1024 + h * 64 + quad * 8;
#pragma unroll
        for (int half = 0; half < 2; half++) {
            float4 a = *(const float4*)(Qg + half * 32);
            float4 c = *(const float4*)(Qg + half * 32 + 4);
            u16 hh, ll;
            float vals[8] = {a.x, a.y, a.z, a.w, c.x, c.y, c.z, c.w};
#pragma unroll
            for (int j = 0; j < 8; j++) {
                split_hl(vals[j] * LOG2E, hh, ll);
                if (half == 0) { qh0[j] = (short)hh; ql0[j] = (short)ll; }
                else           { qh1[j] = (short)hh; ql1[j] = (short)ll; }
            }
        }
    }
    f32x4 O[4] = {};
    f32x4 O4 = {};   // row-sums of P via ones-MFMA -> softmax denominator
    short8 vones;
#pragma unroll
    for (int i = 0; i < 8; i++) vones[i] = (short)0x3f80; // bf16 1.0
    u16* Pw = Pss + wave * 16 * 72;
    int my_q = q0 + wave * 16 + quad * 4;
    const float* bt = bias_tab + h * 4096;
    const float* ma = mask_add + b * 2048;
    // swizzled staging: wave w fills rows [w*16, w*16+16)
    int lr8 = lane >> 3, cb = (lane & 7) ^ (lr8 & 7);
    const u16* gkh = Kh + (size_t)(b * 2048 + wave * 16 + lr8) * 1024 + h * 64 + cb * 8;
    const u16* gkl = Kl + (size_t)(b * 2048 + wave * 16 + lr8) * 1024 + h * 64 + cb * 8;
    const u16* gv  = vT + (size_t)(h * 64 + wave * 16 + lr8) * 4096 + b * 2048 + cb * 8;
    u16* lkh = Khs + wave * 1024;
    u16* lkl = Kls + wave * 1024;
    u16* lv  = Vs + wave * 1024;
    int sw = l15 & 7;
    int swK0 = (quad ^ sw) * 8, swK1 = ((quad + 4) ^ sw) * 8;

    for (int k0 = 0; k0 < 2048; k0 += 64) {
        __syncthreads();
        gld16(gkh + (size_t)k0 * 1024, lkh);
        gld16(gkh + (size_t)k0 * 1024 + 8 * 1024, lkh + 512);
        gld16(gkl + (size_t)k0 * 1024, lkl);
        gld16(gkl + (size_t)k0 * 1024 + 8 * 1024, lkl + 512);
        gld16(gv + k0, lv);
        gld16(gv + k0 + (size_t)8 * 4096, lv + 512);
        __syncthreads();
        float pv[4][4];
#pragma unroll
        for (int t = 0; t < 4; t++) {
            const u16* krow = Khs + (t * 16 + l15) * 64;
            const u16* lrow = Kls + (t * 16 + l15) * 64;
            short8 kh0 = ldf(krow + swK0);
            short8 kh1 = ldf(krow + swK1);
            short8 kl0 = ldf(lrow + swK0);
            short8 kl1 = ldf(lrow + swK1);
            f32x4 z = {0.0f, 0.0f, 0.0f, 0.0f};
            z = __builtin_amdgcn_mfma_f32_16x16x32_bf16(ql0, kh0, z, 0, 0, 0);
            z = __builtin_amdgcn_mfma_f32_16x16x32_bf16(ql1, kh1, z, 0, 0, 0);
            z = __builtin_amdgcn_mfma_f32_16x16x32_bf16(qh0, kl0, z, 0, 0, 0);
            z = __builtin_amdgcn_mfma_f32_16x16x32_bf16(qh1, kl1, z, 0, 0, 0);
            z = __builtin_amdgcn_mfma_f32_16x16x32_bf16(qh0, kh0, z, 0, 0, 0);
            z = __builtin_amdgcn_mfma_f32_16x16x32_bf16(qh1, kh1, z, 0, 0, 0);
            int kcol = k0 + t * 16 + l15;
            float madd = ma[kcol];
#pragma unroll
            for (int r = 0; r < 4; r++)
                pv[t][r] = exp2f(z[r] + bt[kcol - (my_q + r) + 2047] + madd);
        }
#pragma unroll
        for (int t = 0; t < 4; t++)
#pragma unroll
            for (int r = 0; r < 4; r++)
                Pw[(quad * 4 + r) * 72 + t * 16 + l15] = f2b(pv[t][r]);
#pragma unroll
        for (int h2 = 0; h2 < 2; h2++) {
            short8 pf = ldf(Pw + l15 * 72 + h2 * 32 + quad * 8);
#pragma unroll
            for (int nt = 0; nt < 4; nt++) {
                short8 vf = ldf(Vs + (nt * 16 + l15) * 64 + ((h2 * 4 + quad) ^ sw) * 8);
                O[nt] = __builtin_amdgcn_mfma_f32_16x16x32_bf16(pf, vf, O[nt], 0, 0, 0);
            }
            O4 = __builtin_amdgcn_mfma_f32_16x16x32_bf16(pf, vones, O4, 0, 0, 0);
        }
    }
    u16* Cg = Ctx + ((size_t)(b * 2048 + my_q)) * 1024 + h * 64;
#pragma unroll
    for (int nt = 0; nt < 4; nt++)
#pragma unroll
        for (int r = 0; r < 4; r++) {
            float v = O[nt][r] / fmaxf(O4[r], 1e-30f);
            Cg[(size_t)r * 1024 + nt * 16 + l15] = f2b(scrub(v, 1e6f));
        }
}

// ---------------------------------------------------------------------------
extern "C" void kernel_launch(void* const* d_in, const int* in_sizes, int n_in,
                              void* d_out, int out_size, void* d_ws, size_t ws_size,
                              hipStream_t stream) {
    const float* hidden = (const float*)d_in[0];
    const float* mask   = (const float*)d_in[1];
    const float* ln1_w  = (const float*)d_in[2];
    const float* wq     = (const float*)d_in[3];
    const float* wk     = (const float*)d_in[4];
    const float* wv     = (const float*)d_in[5];
    const float* relb   = (const float*)d_in[6];
    const float* wo     = (const float*)d_in[7];
    const float* ln2_w  = (const float*)d_in[8];
    const float* w1     = (const float*)d_in[9];
    const float* w2     = (const float*)d_in[10];
    const float* w_out  = (const float*)d_in[11];
    float* out = (float*)d_out;

    // workspace layout (MB), phase-multiplexed (peak ~64.3 MB):
    //  0- 6 : qkvT            -> woutT (0-8, after out-proj)
    //  6- 8 : woT
    //  8-16 : w1T   16-24 : w2T
    // 24-32 : normed -> ctx -> normed2
    // 32-40 : (free)   \
    // 40-48 : Kh         \ ffg (32-64, FFN phase)
    // 48-56 : Kl         /
    // 56-64 : vT       /
    // 64-   : bias_tab (256K) + mask_add (16K)
    // Q (fp32) lives in d_out until out-proj overwrites it with the trunk.
    char* w = (char*)d_ws;
    const size_t MB = 1u << 20;
    u16*   qkvT    = (u16*)(w + 0 * MB);
    u16*   woutT   = (u16*)(w + 0 * MB);
    u16*   woT     = (u16*)(w + 6 * MB);
    u16*   w1T     = (u16*)(w + 8 * MB);
    u16*   w2T     = (u16*)(w + 16 * MB);
    u16*   normed  = (u16*)(w + 24 * MB);
    u16*   ctx     = (u16*)(w + 24 * MB);
    u16*   normed2 = (u16*)(w + 24 * MB);
    u16*   Kh      = (u16*)(w + 40 * MB);
    u16*   Kl      = (u16*)(w + 48 * MB);
    u16*   vT      = (u16*)(w + 56 * MB);
    u16*   ffg     = (u16*)(w + 32 * MB);
    float* bias_tab = (float*)(w + 64 * MB);
    float* mask_add = (float*)(w + 64 * MB + 256 * 1024);
    float* qb      = (float*)d_out;

    dim3 blk(256);
    // weight transposes fp32 -> bf16 [N][K]; wq/wk/wv into one qkvT [3072][1024]
    transpose_cvt<<<dim3(32, 32), blk, 0, stream>>>(wq, qkvT, 1024, 1024);
    transpose_cvt<<<dim3(32, 32), blk, 0, stream>>>(wk, qkvT + 1024 * 1024, 1024, 1024);
    transpose_cvt<<<dim3(32, 32), blk, 0, stream>>>(wv, qkvT + 2048 * 1024, 1024, 1024);
    transpose_cvt<<<dim3(32, 32), blk, 0, stream>>>(wo, woT, 1024, 1024);
    transpose_cvt<<<dim3(128, 32), blk, 0, stream>>>(w1, w1T, 1024, 4096);
    transpose_cvt<<<dim3(128, 32), blk, 0, stream>>>(w2, w2T, 1024, 4096);
    bias_table_kernel<<<16, 256, 0, stream>>>(relb, mask, bias_tab, mask_add);

    // pre-LN 1 + merged QKV projection (single-plane A)
    rmsnorm_k<<<4096, blk, 0, stream>>>(hidden, ln1_w, normed);
    gemm_qkv<<<dim3(24, 32), blk, 0, stream>>>(normed, qkvT, qb, Kh, Kl, vT);

    // attention (ctx overwrites dead normed region)
    attn_kernel<<<dim3(32, 16, 2), blk, 0, stream>>>(qb, Kh, Kl, vT, bias_tab, mask_add, ctx);

    // output proj + residual -> fp32 trunk in d_out (overwrites qb)
    gemm_bt_res<<<dim3(8, 32), blk, 0, stream>>>(ctx, woT, out, hidden, 4096, 1024, 1024, 1e8f);

    // transpose w_out into now-dead qkvT/woT region
    transpose_cvt<<<dim3(32, 128), blk, 0, stream>>>(w_out, woutT, 4096, 1024);

    // pre-LN 2 + gated FFN + final residual
    rmsnorm_k<<<4096, blk, 0, stream>>>(out, ln2_w, normed2);
    gemm_dual_gelu<<<dim3(32, 32), blk, 0, stream>>>(normed2, w1T, w2T, ffg, 4096, 4096, 1024);
    gemm_bt_res<<<dim3(8, 32), blk, 0, stream>>>(ffg, woutT, out, out, 4096, 1024, 4096, 1e12f);
}

// Round 8
// 510.372 us; speedup vs baseline: 1.0986x; 1.0986x over previous
//
#include <hip/hip_runtime.h>
#include <math.h>

typedef unsigned short u16;
typedef unsigned int u32;
typedef __attribute__((ext_vector_type(8))) short short8; // 8 x bf16 (4 VGPRs)
typedef __attribute__((ext_vector_type(4))) float f32x4;

__device__ __forceinline__ float b2f(u16 u) {
    u32 x = ((u32)u) << 16;
    return __builtin_bit_cast(float, x);
}
__device__ __forceinline__ u16 f2b(float f) { // RNE bf16
    u32 x = __builtin_bit_cast(u32, f);
    u32 r = x + 0x7fffu + ((x >> 16) & 1u);
    return (u16)(r >> 16);
}
__device__ __forceinline__ void split_hl(float x, u16& h, u16& l) {
    u16 hb = f2b(x);
    h = hb;
    l = f2b(x - b2f(hb));
}
// fast gelu_new: tanh(y) = 1 - 2/(1+e^{2y}) via __expf (inf-safe)
__device__ __forceinline__ float gelu_new_f(float x) {
    const float c = 0.7978845608028654f;
    float y = c * (x + 0.044715f * x * x * x);
    float t = 1.0f - 2.0f / (1.0f + __expf(2.0f * y));
    return 0.5f * x * (1.0f + t);
}
// breadcrumb: NaN OR inf -> stage-distinctive magnitude
__device__ __forceinline__ float scrub(float v, float s) {
    return (fabsf(v) < 1e25f) ? v : s;
}
// async global->LDS, 16B per lane; LDS dest = wave-uniform base + lane*16
__device__ __forceinline__ void gld16(const void* g, void* l) {
    __builtin_amdgcn_global_load_lds((const __attribute__((address_space(1))) u32*)g,
                                     (__attribute__((address_space(3))) u32*)l,
                                     16, 0, 0);
}
__device__ __forceinline__ short8 ldf(const u16* p) { return *(const short8*)p; }

// -------- transpose+convert: src fp32 [R][C] -> dst bf16 [C][R] ------------
__global__ __launch_bounds__(256) void transpose_cvt(const float* __restrict__ src,
                                                     u16* __restrict__ dst, int R, int C) {
    __shared__ u16 t[32][33];
    int c0 = blockIdx.x * 32, r0 = blockIdx.y * 32;
    int x = threadIdx.x & 31, y = threadIdx.x >> 5; // 32 x 8
#pragma unroll
    for (int i = 0; i < 32; i += 8)
        t[y + i][x] = f2b(src[(size_t)(r0 + y + i) * C + c0 + x]);
    __syncthreads();
#pragma unroll
    for (int i = 0; i < 32; i += 8)
        dst[(size_t)(c0 + y + i) * R + r0 + x] = t[x][y + i];
}

// -------- T5 rel-pos bias table + additive mask (fp32 inputs) --------------
// tab and mask_add are pre-scaled by log2(e); mask_add also folds the softmax
// fixed shift (-20). Attention computes p = exp2(z' + b' + m') == e^(z+b+m-20).
__global__ void bias_table_kernel(const float* __restrict__ rel_bias,
                                  const float* __restrict__ mask,
                                  float* __restrict__ tab,
                                  float* __restrict__ mask_add) {
    const float LOG2E = 1.4426950408889634f;
    int idx = blockIdx.x * 256 + threadIdx.x; // 0..4095
    if (idx < 4095) {
        int rel = idx - 2047;
        int ret = rel > 0 ? 16 : 0;
        int n = rel < 0 ? -rel : rel;
        int bucket;
        if (n < 8) {
            bucket = ret + n;
        } else {
            int v = 8 + (int)(logf((float)n * 0.125f) * (8.0f / 2.7725887222397811f));
            v = v < 15 ? v : 15;
            bucket = ret + v;
        }
#pragma unroll
        for (int h = 0; h < 16; h++)
            tab[h * 4096 + idx] = rel_bias[bucket * 16 + h] * LOG2E;
    }
    if (idx < 4096)
        mask_add[idx] = ((1.0f - mask[idx]) * -10000.0f - 20.0f) * LOG2E;
}

// -------- RMSNorm: fp32 in -> bf16 ----------------------------------------
__global__ __launch_bounds__(256) void rmsnorm_k(const float* __restrict__ X,
                                                 const float* __restrict__ W,
                                                 u16* __restrict__ Y) {
    __shared__ float red[4];
    int row = blockIdx.x, tid = threadIdx.x;
    const float* xr = X + (size_t)row * 1024;
    float4 x = *(const float4*)(xr + tid * 4);
    float ss = x.x * x.x + x.y * x.y + x.z * x.z + x.w * x.w;
#pragma unroll
    for (int off = 32; off; off >>= 1) ss += __shfl_xor(ss, off, 64);
    if ((tid & 63) == 0) red[tid >> 6] = ss;
    __syncthreads();
    float tot = red[0] + red[1] + red[2] + red[3];
    float s = rsqrtf(tot * (1.0f / 1024.0f) + 1e-6f);
    float4 w4 = *(const float4*)(W + tid * 4);
    float y0 = scrub(x.x * s * w4.x, 1e3f);
    float y1 = scrub(x.y * s * w4.y, 1e3f);
    float y2 = scrub(x.z * s * w4.z, 1e3f);
    float y3 = scrub(x.w * s * w4.w, 1e3f);
    uint2 o;
    o.x = (u32)f2b(y0) | ((u32)f2b(y1) << 16);
    o.y = (u32)f2b(y2) | ((u32)f2b(y3) << 16);
    *(uint2*)(Y + (size_t)row * 1024 + tid * 4) = o;
}

// ===== BK=64 XOR-swizzled staging ==========================================
// LDS tile: rows x 64 cols bf16, row stride 128 B. 16B block b of row r holds
// global col-block b^(r&7) -> conflict-free ds_read_b128 fragment loads.

// -------- merged QKV GEMM (single-plane A), K=1024, N=3072 -----------------
// epilogue: Q -> fp32 qb; K -> bf16 hi/lo planes; V -> transposed bf16 vT
__global__ __launch_bounds__(256) void gemm_qkv(const u16* __restrict__ A,
                                                const u16* __restrict__ Bt,
                                                float* __restrict__ qb,
                                                u16* __restrict__ Kh,
                                                u16* __restrict__ Kl,
                                                u16* __restrict__ vT) {
    const int K = 1024;
    __shared__ __align__(16) u16 As[128 * 64];
    __shared__ __align__(16) u16 Bs[128 * 64];
    int tid = threadIdx.x;
    int wave = tid >> 6, lane = tid & 63, quad = lane >> 4, l15 = lane & 15;
    int bm = blockIdx.y * 128, bn = blockIdx.x * 128;
    int wm = (wave >> 1) * 64, wn = (wave & 1) * 64;
    f32x4 acc[4][4] = {};
    int lr = lane >> 3, cb = (lane & 7) ^ (lr & 7);
    const u16* ga = A + (size_t)(bm + wave * 32 + lr) * K + cb * 8;
    const u16* gb = Bt + (size_t)(bn + wave * 32 + lr) * K + cb * 8;
    u16* la = As + wave * 2048;
    u16* lb = Bs + wave * 2048;
    int swz = l15 & 7;
    for (int k0 = 0; k0 < K; k0 += 64) {
        __syncthreads();
#pragma unroll
        for (int g = 0; g < 4; g++) {
            gld16(ga + k0 + (size_t)(g * 8) * K, la + g * 512);
            gld16(gb + k0 + (size_t)(g * 8) * K, lb + g * 512);
        }
        __syncthreads();
#pragma unroll
        for (int s = 0; s < 2; s++) {
            int kb = ((s * 4 + quad) ^ swz) * 8;
            short8 af[4], bf[4];
#pragma unroll
            for (int i = 0; i < 4; i++)
                af[i] = ldf(As + (wm + i * 16 + l15) * 64 + kb);
#pragma unroll
            for (int j = 0; j < 4; j++)
                bf[j] = ldf(Bs + (wn + j * 16 + l15) * 64 + kb);
#pragma unroll
            for (int i = 0; i < 4; i++)
#pragma unroll
                for (int j = 0; j < 4; j++)
                    acc[i][j] = __builtin_amdgcn_mfma_f32_16x16x32_bf16(af[i], bf[j], acc[i][j], 0, 0, 0);
        }
    }
    if (bn < 1024) {            // Q -> fp32
#pragma unroll
        for (int i = 0; i < 4; i++)
#pragma unroll
            for (int j = 0; j < 4; j++) {
                int col = bn + wn + j * 16 + l15;
#pragma unroll
                for (int r = 0; r < 4; r++) {
                    int row = bm + wm + i * 16 + quad * 4 + r;
                    qb[(size_t)row * 1024 + col] = scrub(acc[i][j][r], 1e4f);
                }
            }
    } else if (bn < 2048) {     // K -> hi/lo bf16 planes
#pragma unroll
        for (int i = 0; i < 4; i++)
#pragma unroll
            for (int j = 0; j < 4; j++) {
                int col = bn - 1024 + wn + j * 16 + l15;
#pragma unroll
                for (int r = 0; r < 4; r++) {
                    int row = bm + wm + i * 16 + quad * 4 + r;
                    u16 hh, ll;
                    split_hl(scrub(acc[i][j][r], 1e4f), hh, ll);
                    Kh[(size_t)row * 1024 + col] = hh;
                    Kl[(size_t)row * 1024 + col] = ll;
                }
            }
    } else {                    // V -> transposed bf16 vT[d][B*S]
#pragma unroll
        for (int i = 0; i < 4; i++)
#pragma unroll
            for (int j = 0; j < 4; j++) {
                int col = bn - 2048 + wn + j * 16 + l15;
                int row0 = bm + wm + i * 16 + quad * 4;
                ushort4 p;
                p.x = f2b(scrub(acc[i][j][0], 1e4f));
                p.y = f2b(scrub(acc[i][j][1], 1e4f));
                p.z = f2b(scrub(acc[i][j][2], 1e4f));
                p.w = f2b(scrub(acc[i][j][3], 1e4f));
                *(ushort4*)(vT + (size_t)col * 4096 + row0) = p;
            }
    }
}

// -------- GEMM: C fp32 = A bf16 [M,K] @ Bt [N,K]^T + Res fp32, BK=64 -------
__global__ __launch_bounds__(256) void gemm_bt_res(const u16* __restrict__ A,
                                                   const u16* __restrict__ Bt,
                                                   float* __restrict__ C,
                                                   const float* __restrict__ Res,
                                                   int M, int N, int K, float sval) {
    __shared__ __align__(16) u16 As[128 * 64];
    __shared__ __align__(16) u16 Bs[128 * 64];
    int tid = threadIdx.x;
    int wave = tid >> 6, lane = tid & 63, quad = lane >> 4, l15 = lane & 15;
    int bm = blockIdx.y * 128, bn = blockIdx.x * 128;
    int wm = (wave >> 1) * 64, wn = (wave & 1) * 64;
    f32x4 acc[4][4] = {};
    int lr = lane >> 3, cb = (lane & 7) ^ (lr & 7);
    const u16* ga = A + (size_t)(bm + wave * 32 + lr) * K + cb * 8;
    const u16* gb = Bt + (size_t)(bn + wave * 32 + lr) * K + cb * 8;
    u16* la = As + wave * 2048;
    u16* lb = Bs + wave * 2048;
    int swz = l15 & 7;
    for (int k0 = 0; k0 < K; k0 += 64) {
        __syncthreads();
#pragma unroll
        for (int g = 0; g < 4; g++) {
            gld16(ga + k0 + (size_t)(g * 8) * K, la + g * 512);
            gld16(gb + k0 + (size_t)(g * 8) * K, lb + g * 512);
        }
        __syncthreads();
#pragma unroll
        for (int s = 0; s < 2; s++) {
            int kb = ((s * 4 + quad) ^ swz) * 8;
            short8 af[4], bf[4];
#pragma unroll
            for (int i = 0; i < 4; i++)
                af[i] = ldf(As + (wm + i * 16 + l15) * 64 + kb);
#pragma unroll
            for (int j = 0; j < 4; j++)
                bf[j] = ldf(Bs + (wn + j * 16 + l15) * 64 + kb);
#pragma unroll
            for (int i = 0; i < 4; i++)
#pragma unroll
                for (int j = 0; j < 4; j++)
                    acc[i][j] = __builtin_amdgcn_mfma_f32_16x16x32_bf16(af[i], bf[j], acc[i][j], 0, 0, 0);
        }
    }
#pragma unroll
    for (int i = 0; i < 4; i++)
#pragma unroll
        for (int j = 0; j < 4; j++) {
            int col = bn + wn + j * 16 + l15;
#pragma unroll
            for (int r = 0; r < 4; r++) {
                int row = bm + wm + i * 16 + quad * 4 + r;
                float v = acc[i][j][r] + Res[(size_t)row * N + col];
                C[(size_t)row * N + col] = scrub(v, sval);
            }
        }
}

// -------- Dual GEMM + gated GELU: C = gelu(A@B1t^T) * (A@B2t^T), BK=64 -----
__global__ __launch_bounds__(256) void gemm_dual_gelu(const u16* __restrict__ A,
                                                      const u16* __restrict__ B1t,
                                                      const u16* __restrict__ B2t,
                                                      u16* __restrict__ C,
                                                      int M, int N, int K) {
    __shared__ __align__(16) u16 As[128 * 64];
    __shared__ __align__(16) u16 B1s[128 * 64];
    __shared__ __align__(16) u16 B2s[128 * 64];
    int tid = threadIdx.x;
    int wave = tid >> 6, lane = tid & 63, quad = lane >> 4, l15 = lane & 15;
    int bm = blockIdx.y * 128, bn = blockIdx.x * 128;
    int wm = (wave >> 1) * 64, wn = (wave & 1) * 64;
    f32x4 acc1[4][4] = {};
    f32x4 acc2[4][4] = {};
    int lr = lane >> 3, cb = (lane & 7) ^ (lr & 7);
    const u16* ga = A + (size_t)(bm + wave * 32 + lr) * K + cb * 8;
    const u16* g1 = B1t + (size_t)(bn + wave * 32 + lr) * K + cb * 8;
    const u16* g2 = B2t + (size_t)(bn + wave * 32 + lr) * K + cb * 8;
    u16* la = As + wave * 2048;
    u16* l1 = B1s + wave * 2048;
    u16* l2 = B2s + wave * 2048;
    int swz = l15 & 7;
    for (int k0 = 0; k0 < K; k0 += 64) {
        __syncthreads();
#pragma unroll
        for (int g = 0; g < 4; g++) {
            gld16(ga + k0 + (size_t)(g * 8) * K, la + g * 512);
            gld16(g1 + k0 + (size_t)(g * 8) * K, l1 + g * 512);
            gld16(g2 + k0 + (size_t)(g * 8) * K, l2 + g * 512);
        }
        __syncthreads();
#pragma unroll
        for (int s = 0; s < 2; s++) {
            int kb = ((s * 4 + quad) ^ swz) * 8;
            short8 af[4], b1f[4], b2f_[4];
#pragma unroll
            for (int i = 0; i < 4; i++)
                af[i] = ldf(As + (wm + i * 16 + l15) * 64 + kb);
#pragma unroll
            for (int j = 0; j < 4; j++) {
                b1f[j] = ldf(B1s + (wn + j * 16 + l15) * 64 + kb);
                b2f_[j] = ldf(B2s + (wn + j * 16 + l15) * 64 + kb);
            }
#pragma unroll
            for (int i = 0; i < 4; i++)
#pragma unroll
                for (int j = 0; j < 4; j++) {
                    acc1[i][j] = __builtin_amdgcn_mfma_f32_16x16x32_bf16(af[i], b1f[j], acc1[i][j], 0, 0, 0);
                    acc2[i][j] = __builtin_amdgcn_mfma_f32_16x16x32_bf16(af[i], b2f_[j], acc2[i][j], 0, 0, 0);
                }
        }
    }
#pragma unroll
    for (int i = 0; i < 4; i++)
#pragma unroll
        for (int j = 0; j < 4; j++) {
            int col = bn + wn + j * 16 + l15;
#pragma unroll
            for (int r = 0; r < 4; r++) {
                int row = bm + wm + i * 16 + quad * 4 + r;
                float v = gelu_new_f(acc1[i][j][r]) * acc2[i][j][r];
                C[(size_t)row * N + col] = f2b(scrub(v, 1e10f));
            }
        }
}

// -------- MFMA flash attention v4 ------------------------------------------
// grid (S/64, H, B), 256 thr. KT=64, Q A-frags direct from global, exp2
// softmax, MFMA row-sum denominator, XOR-swizzled K/V staging.
// T5 bucket saturation: for |rel| >= 91 the bias is constant per side, so
// tiles with |k0-q0| >= 192 (block-uniform!) skip the 16 table gathers/iter.
__global__ __launch_bounds__(256) void attn_kernel(const float* __restrict__ Qb,
                                                   const u16* __restrict__ Kh,
                                                   const u16* __restrict__ Kl,
                                                   const u16* __restrict__ vT,
                                                   const float* __restrict__ bias_tab,
                                                   const float* __restrict__ mask_add,
                                                   u16* __restrict__ Ctx) {
    __shared__ __align__(16) u16 Khs[64 * 64];  // swizzled: blk ^= (row&7)
    __shared__ __align__(16) u16 Kls[64 * 64];
    __shared__ __align__(16) u16 Vs[64 * 64];   // [d][kv], swizzled
    __shared__ __align__(16) u16 Pss[4 * 16 * 72];
    const float LOG2E = 1.4426950408889634f;
    int tid = threadIdx.x, wave = tid >> 6, lane = tid & 63;
    int quad = lane >> 4, l15 = lane & 15;
    int h = blockIdx.y, b = blockIdx.z;
    int q0 = blockIdx.x * 64;
    // Q A-fragment direct load: lane owns q-row (wave*16+l15), k = half*32+quad*8+j
    short8 qh0, qh1, ql0, ql1;
    {
        const float* Qg = Qb + (size_t)(b * 2048 + q0 + wave * 16 + l15) * 1024 + h * 64 + quad * 8;
#pragma unroll
        for (int half = 0; half < 2; half++) {
            float4 a = *(const float4*)(Qg + half * 32);
            float4 c = *(const float4*)(Qg + half * 32 + 4);
            u16 hh, ll;
            float vals[8] = {a.x, a.y, a.z, a.w, c.x, c.y, c.z, c.w};
#pragma unroll
            for (int j = 0; j < 8; j++) {
                split_hl(vals[j] * LOG2E, hh, ll);
                if (half == 0) { qh0[j] = (short)hh; ql0[j] = (short)ll; }
                else           { qh1[j] = (short)hh; ql1[j] = (short)ll; }
            }
        }
    }
    f32x4 O[4] = {};
    f32x4 O4 = {};   // row-sums of P via ones-MFMA -> softmax denominator
    short8 vones;
#pragma unroll
    for (int i = 0; i < 8; i++) vones[i] = (short)0x3f80; // bf16 1.0
    u16* Pw = Pss + wave * 16 * 72;
    int my_q = q0 + wave * 16 + quad * 4;
    const float* bt = bias_tab + h * 4096;
    const float* ma = mask_add + b * 2048;
    float bsat_neg = bt[0];      // bias for rel <= -91 (saturated)
    float bsat_pos = bt[4094];   // bias for rel >= +91 (saturated)
    // swizzled staging: wave w fills rows [w*16, w*16+16)
    int lr8 = lane >> 3, cb = (lane & 7) ^ (lr8 & 7);
    const u16* gkh = Kh + (size_t)(b * 2048 + wave * 16 + lr8) * 1024 + h * 64 + cb * 8;
    const u16* gkl = Kl + (size_t)(b * 2048 + wave * 16 + lr8) * 1024 + h * 64 + cb * 8;
    const u16* gv  = vT + (size_t)(h * 64 + wave * 16 + lr8) * 4096 + b * 2048 + cb * 8;
    u16* lkh = Khs + wave * 1024;
    u16* lkl = Kls + wave * 1024;
    u16* lv  = Vs + wave * 1024;
    int sw = l15 & 7;
    int swK0 = (quad ^ sw) * 8, swK1 = ((quad + 4) ^ sw) * 8;

    for (int k0 = 0; k0 < 2048; k0 += 64) {
        __syncthreads();
        gld16(gkh + (size_t)k0 * 1024, lkh);
        gld16(gkh + (size_t)k0 * 1024 + 8 * 1024, lkh + 512);
        gld16(gkl + (size_t)k0 * 1024, lkl);
        gld16(gkl + (size_t)k0 * 1024 + 8 * 1024, lkl + 512);
        gld16(gv + k0, lv);
        gld16(gv + k0 + (size_t)8 * 4096, lv + 512);
        __syncthreads();
        float pv[4][4];
        int dq = k0 - q0;
        if (dq >= 192 || dq <= -192) {
            // saturated-bias fast path: additive term is r-independent
            float bsat = dq > 0 ? bsat_pos : bsat_neg;
#pragma unroll
            for (int t = 0; t < 4; t++) {
                const u16* krow = Khs + (t * 16 + l15) * 64;
                const u16* lrow = Kls + (t * 16 + l15) * 64;
                short8 kh0 = ldf(krow + swK0);
                short8 kh1 = ldf(krow + swK1);
                short8 kl0 = ldf(lrow + swK0);
                short8 kl1 = ldf(lrow + swK1);
                f32x4 z = {0.0f, 0.0f, 0.0f, 0.0f};
                z = __builtin_amdgcn_mfma_f32_16x16x32_bf16(ql0, kh0, z, 0, 0, 0);
                z = __builtin_amdgcn_mfma_f32_16x16x32_bf16(ql1, kh1, z, 0, 0, 0);
                z = __builtin_amdgcn_mfma_f32_16x16x32_bf16(qh0, kl0, z, 0, 0, 0);
                z = __builtin_amdgcn_mfma_f32_16x16x32_bf16(qh1, kl1, z, 0, 0, 0);
                z = __builtin_amdgcn_mfma_f32_16x16x32_bf16(qh0, kh0, z, 0, 0, 0);
                z = __builtin_amdgcn_mfma_f32_16x16x32_bf16(qh1, kh1, z, 0, 0, 0);
                float c = ma[k0 + t * 16 + l15] + bsat;
#pragma unroll
                for (int r = 0; r < 4; r++)
                    pv[t][r] = exp2f(z[r] + c);
            }
        } else {
            // diagonal tiles: per-element bucket table gather
#pragma unroll
            for (int t = 0; t < 4; t++) {
                const u16* krow = Khs + (t * 16 + l15) * 64;
                const u16* lrow = Kls + (t * 16 + l15) * 64;
                short8 kh0 = ldf(krow + swK0);
                short8 kh1 = ldf(krow + swK1);
                short8 kl0 = ldf(lrow + swK0);
                short8 kl1 = ldf(lrow + swK1);
                f32x4 z = {0.0f, 0.0f, 0.0f, 0.0f};
                z = __builtin_amdgcn_mfma_f32_16x16x32_bf16(ql0, kh0, z, 0, 0, 0);
                z = __builtin_amdgcn_mfma_f32_16x16x32_bf16(ql1, kh1, z, 0, 0, 0);
                z = __builtin_amdgcn_mfma_f32_16x16x32_bf16(qh0, kl0, z, 0, 0, 0);
                z = __builtin_amdgcn_mfma_f32_16x16x32_bf16(qh1, kl1, z, 0, 0, 0);
                z = __builtin_amdgcn_mfma_f32_16x16x32_bf16(qh0, kh0, z, 0, 0, 0);
                z = __builtin_amdgcn_mfma_f32_16x16x32_bf16(qh1, kh1, z, 0, 0, 0);
                int kcol = k0 + t * 16 + l15;
                float madd = ma[kcol];
#pragma unroll
                for (int r = 0; r < 4; r++)
                    pv[t][r] = exp2f(z[r] + bt[kcol - (my_q + r) + 2047] + madd);
            }
        }
#pragma unroll
        for (int t = 0; t < 4; t++)
#pragma unroll
            for (int r = 0; r < 4; r++)
                Pw[(quad * 4 + r) * 72 + t * 16 + l15] = f2b(pv[t][r]);
#pragma unroll
        for (int h2 = 0; h2 < 2; h2++) {
            short8 pf = ldf(Pw + l15 * 72 + h2 * 32 + quad * 8);
#pragma unroll
            for (int nt = 0; nt < 4; nt++) {
                short8 vf = ldf(Vs + (nt * 16 + l15) * 64 + ((h2 * 4 + quad) ^ sw) * 8);
                O[nt] = __builtin_amdgcn_mfma_f32_16x16x32_bf16(pf, vf, O[nt], 0, 0, 0);
            }
            O4 = __builtin_amdgcn_mfma_f32_16x16x32_bf16(pf, vones, O4, 0, 0, 0);
        }
    }
    u16* Cg = Ctx + ((size_t)(b * 2048 + my_q)) * 1024 + h * 64;
#pragma unroll
    for (int nt = 0; nt < 4; nt++)
#pragma unroll
        for (int r = 0; r < 4; r++) {
            float v = O[nt][r] / fmaxf(O4[r], 1e-30f);
            Cg[(size_t)r * 1024 + nt * 16 + l15] = f2b(scrub(v, 1e6f));
        }
}

// ---------------------------------------------------------------------------
extern "C" void kernel_launch(void* const* d_in, const int* in_sizes, int n_in,
                              void* d_out, int out_size, void* d_ws, size_t ws_size,
                              hipStream_t stream) {
    const float* hidden = (const float*)d_in[0];
    const float* mask   = (const float*)d_in[1];
    const float* ln1_w  = (const float*)d_in[2];
    const float* wq     = (const float*)d_in[3];
    const float* wk     = (const float*)d_in[4];
    const float* wv     = (const float*)d_in[5];
    const float* relb   = (const float*)d_in[6];
    const float* wo     = (const float*)d_in[7];
    const float* ln2_w  = (const float*)d_in[8];
    const float* w1     = (const float*)d_in[9];
    const float* w2     = (const float*)d_in[10];
    const float* w_out  = (const float*)d_in[11];
    float* out = (float*)d_out;

    // workspace layout (MB), phase-multiplexed (peak ~64.3 MB):
    //  0- 6 : qkvT            -> woutT (0-8, after out-proj)
    //  6- 8 : woT
    //  8-16 : w1T   16-24 : w2T
    // 24-32 : normed -> ctx -> normed2
    // 32-40 : (free)   \
    // 40-48 : Kh         \ ffg (32-64, FFN phase)
    // 48-56 : Kl         /
    // 56-64 : vT       /
    // 64-   : bias_tab (256K) + mask_add (16K)
    // Q (fp32) lives in d_out until out-proj overwrites it with the trunk.
    char* w = (char*)d_ws;
    const size_t MB = 1u << 20;
    u16*   qkvT    = (u16*)(w + 0 * MB);
    u16*   woutT   = (u16*)(w + 0 * MB);
    u16*   woT     = (u16*)(w + 6 * MB);
    u16*   w1T     = (u16*)(w + 8 * MB);
    u16*   w2T     = (u16*)(w + 16 * MB);
    u16*   normed  = (u16*)(w + 24 * MB);
    u16*   ctx     = (u16*)(w + 24 * MB);
    u16*   normed2 = (u16*)(w + 24 * MB);
    u16*   Kh      = (u16*)(w + 40 * MB);
    u16*   Kl      = (u16*)(w + 48 * MB);
    u16*   vT      = (u16*)(w + 56 * MB);
    u16*   ffg     = (u16*)(w + 32 * MB);
    float* bias_tab = (float*)(w + 64 * MB);
    float* mask_add = (float*)(w + 64 * MB + 256 * 1024);
    float* qb      = (float*)d_out;

    dim3 blk(256);
    // weight transposes fp32 -> bf16 [N][K]; wq/wk/wv into one qkvT [3072][1024]
    transpose_cvt<<<dim3(32, 32), blk, 0, stream>>>(wq, qkvT, 1024, 1024);
    transpose_cvt<<<dim3(32, 32), blk, 0, stream>>>(wk, qkvT + 1024 * 1024, 1024, 1024);
    transpose_cvt<<<dim3(32, 32), blk, 0, stream>>>(wv, qkvT + 2048 * 1024, 1024, 1024);
    transpose_cvt<<<dim3(32, 32), blk, 0, stream>>>(wo, woT, 1024, 1024);
    transpose_cvt<<<dim3(128, 32), blk, 0, stream>>>(w1, w1T, 1024, 4096);
    transpose_cvt<<<dim3(128, 32), blk, 0, stream>>>(w2, w2T, 1024, 4096);
    bias_table_kernel<<<16, 256, 0, stream>>>(relb, mask, bias_tab, mask_add);

    // pre-LN 1 + merged QKV projection (single-plane A)
    rmsnorm_k<<<4096, blk, 0, stream>>>(hidden, ln1_w, normed);
    gemm_qkv<<<dim3(24, 32), blk, 0, stream>>>(normed, qkvT, qb, Kh, Kl, vT);

    // attention (ctx overwrites dead normed region)
    attn_kernel<<<dim3(32, 16, 2), blk, 0, stream>>>(qb, Kh, Kl, vT, bias_tab, mask_add, ctx);

    // output proj + residual -> fp32 trunk in d_out (overwrites qb)
    gemm_bt_res<<<dim3(8, 32), blk, 0, stream>>>(ctx, woT, out, hidden, 4096, 1024, 1024, 1e8f);

    // transpose w_out into now-dead qkvT/woT region
    transpose_cvt<<<dim3(32, 128), blk, 0, stream>>>(w_out, woutT, 4096, 1024);

    // pre-LN 2 + gated FFN + final residual
    rmsnorm_k<<<4096, blk, 0, stream>>>(out, ln2_w, normed2);
    gemm_dual_gelu<<<dim3(32, 32), blk, 0, stream>>>(normed2, w1T, w2T, ffg, 4096, 4096, 1024);
    gemm_bt_res<<<dim3(8, 32), blk, 0, stream>>>(ffg, woutT, out, out, 4096, 1024, 4096, 1e12f);
}

// Round 9
// 506.640 us; speedup vs baseline: 1.1067x; 1.0074x over previous
//
#include <hip/hip_runtime.h>
#include <math.h>

typedef unsigned short u16;
typedef unsigned int u32;
typedef __attribute__((ext_vector_type(8))) short short8; // 8 x bf16 (4 VGPRs)
typedef __attribute__((ext_vector_type(4))) float f32x4;

__device__ __forceinline__ float b2f(u16 u) {
    u32 x = ((u32)u) << 16;
    return __builtin_bit_cast(float, x);
}
__device__ __forceinline__ u16 f2b(float f) { // RNE bf16
    u32 x = __builtin_bit_cast(u32, f);
    u32 r = x + 0x7fffu + ((x >> 16) & 1u);
    return (u16)(r >> 16);
}
__device__ __forceinline__ void split_hl(float x, u16& h, u16& l) {
    u16 hb = f2b(x);
    h = hb;
    l = f2b(x - b2f(hb));
}
// fast gelu_new: tanh(y) = 1 - 2/(1+e^{2y}) via __expf (inf-safe)
__device__ __forceinline__ float gelu_new_f(float x) {
    const float c = 0.7978845608028654f;
    float y = c * (x + 0.044715f * x * x * x);
    float t = 1.0f - 2.0f / (1.0f + __expf(2.0f * y));
    return 0.5f * x * (1.0f + t);
}
// breadcrumb: NaN OR inf -> stage-distinctive magnitude
__device__ __forceinline__ float scrub(float v, float s) {
    return (fabsf(v) < 1e25f) ? v : s;
}
// async global->LDS, 16B per lane; LDS dest = wave-uniform base + lane*16
__device__ __forceinline__ void gld16(const void* g, void* l) {
    __builtin_amdgcn_global_load_lds((const __attribute__((address_space(1))) u32*)g,
                                     (__attribute__((address_space(3))) u32*)l,
                                     16, 0, 0);
}
__device__ __forceinline__ short8 ldf(const u16* p) { return *(const short8*)p; }

// -------- transpose+convert: src fp32 [R][C] -> dst bf16 [C][R] ------------
__global__ __launch_bounds__(256) void transpose_cvt(const float* __restrict__ src,
                                                     u16* __restrict__ dst, int R, int C) {
    __shared__ u16 t[32][33];
    int c0 = blockIdx.x * 32, r0 = blockIdx.y * 32;
    int x = threadIdx.x & 31, y = threadIdx.x >> 5; // 32 x 8
#pragma unroll
    for (int i = 0; i < 32; i += 8)
        t[y + i][x] = f2b(src[(size_t)(r0 + y + i) * C + c0 + x]);
    __syncthreads();
#pragma unroll
    for (int i = 0; i < 32; i += 8)
        dst[(size_t)(c0 + y + i) * R + r0 + x] = t[x][y + i];
}

// -------- T5 rel-pos bias table + additive mask (fp32 inputs) --------------
// tab and mask_add are pre-scaled by log2(e); mask_add also folds the softmax
// fixed shift (-20). Attention computes p = exp2(z' + b' + m') == e^(z+b+m-20).
__global__ void bias_table_kernel(const float* __restrict__ rel_bias,
                                  const float* __restrict__ mask,
                                  float* __restrict__ tab,
                                  float* __restrict__ mask_add) {
    const float LOG2E = 1.4426950408889634f;
    int idx = blockIdx.x * 256 + threadIdx.x; // 0..4095
    if (idx < 4095) {
        int rel = idx - 2047;
        int ret = rel > 0 ? 16 : 0;
        int n = rel < 0 ? -rel : rel;
        int bucket;
        if (n < 8) {
            bucket = ret + n;
        } else {
            int v = 8 + (int)(logf((float)n * 0.125f) * (8.0f / 2.7725887222397811f));
            v = v < 15 ? v : 15;
            bucket = ret + v;
        }
#pragma unroll
        for (int h = 0; h < 16; h++)
            tab[h * 4096 + idx] = rel_bias[bucket * 16 + h] * LOG2E;
    }
    if (idx < 4096)
        mask_add[idx] = ((1.0f - mask[idx]) * -10000.0f - 20.0f) * LOG2E;
}

// -------- RMSNorm: fp32 in -> bf16 ----------------------------------------
__global__ __launch_bounds__(256) void rmsnorm_k(const float* __restrict__ X,
                                                 const float* __restrict__ W,
                                                 u16* __restrict__ Y) {
    __shared__ float red[4];
    int row = blockIdx.x, tid = threadIdx.x;
    const float* xr = X + (size_t)row * 1024;
    float4 x = *(const float4*)(xr + tid * 4);
    float ss = x.x * x.x + x.y * x.y + x.z * x.z + x.w * x.w;
#pragma unroll
    for (int off = 32; off; off >>= 1) ss += __shfl_xor(ss, off, 64);
    if ((tid & 63) == 0) red[tid >> 6] = ss;
    __syncthreads();
    float tot = red[0] + red[1] + red[2] + red[3];
    float s = rsqrtf(tot * (1.0f / 1024.0f) + 1e-6f);
    float4 w4 = *(const float4*)(W + tid * 4);
    float y0 = scrub(x.x * s * w4.x, 1e3f);
    float y1 = scrub(x.y * s * w4.y, 1e3f);
    float y2 = scrub(x.z * s * w4.z, 1e3f);
    float y3 = scrub(x.w * s * w4.w, 1e3f);
    uint2 o;
    o.x = (u32)f2b(y0) | ((u32)f2b(y1) << 16);
    o.y = (u32)f2b(y2) | ((u32)f2b(y3) << 16);
    *(uint2*)(Y + (size_t)row * 1024 + tid * 4) = o;
}

// ===== BK=64 XOR-swizzled staging ==========================================
// LDS tile: rows x 64 cols bf16, row stride 128 B. 16B block b of row r holds
// global col-block b^(r&7) -> conflict-free ds_read_b128 fragment loads.

// -------- merged QKV GEMM (single-plane A), K=1024, N=3072 -----------------
// epilogue: Q -> fp32 qb; K -> bf16 hi/lo planes; V -> transposed bf16 vT
__global__ __launch_bounds__(256) void gemm_qkv(const u16* __restrict__ A,
                                                const u16* __restrict__ Bt,
                                                float* __restrict__ qb,
                                                u16* __restrict__ Kh,
                                                u16* __restrict__ Kl,
                                                u16* __restrict__ vT) {
    const int K = 1024;
    __shared__ __align__(16) u16 As[128 * 64];
    __shared__ __align__(16) u16 Bs[128 * 64];
    int tid = threadIdx.x;
    int wave = tid >> 6, lane = tid & 63, quad = lane >> 4, l15 = lane & 15;
    int bm = blockIdx.y * 128, bn = blockIdx.x * 128;
    int wm = (wave >> 1) * 64, wn = (wave & 1) * 64;
    f32x4 acc[4][4] = {};
    int lr = lane >> 3, cb = (lane & 7) ^ (lr & 7);
    const u16* ga = A + (size_t)(bm + wave * 32 + lr) * K + cb * 8;
    const u16* gb = Bt + (size_t)(bn + wave * 32 + lr) * K + cb * 8;
    u16* la = As + wave * 2048;
    u16* lb = Bs + wave * 2048;
    int swz = l15 & 7;
    for (int k0 = 0; k0 < K; k0 += 64) {
        __syncthreads();
#pragma unroll
        for (int g = 0; g < 4; g++) {
            gld16(ga + k0 + (size_t)(g * 8) * K, la + g * 512);
            gld16(gb + k0 + (size_t)(g * 8) * K, lb + g * 512);
        }
        __syncthreads();
#pragma unroll
        for (int s = 0; s < 2; s++) {
            int kb = ((s * 4 + quad) ^ swz) * 8;
            short8 af[4], bf[4];
#pragma unroll
            for (int i = 0; i < 4; i++)
                af[i] = ldf(As + (wm + i * 16 + l15) * 64 + kb);
#pragma unroll
            for (int j = 0; j < 4; j++)
                bf[j] = ldf(Bs + (wn + j * 16 + l15) * 64 + kb);
#pragma unroll
            for (int i = 0; i < 4; i++)
#pragma unroll
                for (int j = 0; j < 4; j++)
                    acc[i][j] = __builtin_amdgcn_mfma_f32_16x16x32_bf16(af[i], bf[j], acc[i][j], 0, 0, 0);
        }
    }
    if (bn < 1024) {            // Q -> fp32
#pragma unroll
        for (int i = 0; i < 4; i++)
#pragma unroll
            for (int j = 0; j < 4; j++) {
                int col = bn + wn + j * 16 + l15;
#pragma unroll
                for (int r = 0; r < 4; r++) {
                    int row = bm + wm + i * 16 + quad * 4 + r;
                    qb[(size_t)row * 1024 + col] = scrub(acc[i][j][r], 1e4f);
                }
            }
    } else if (bn < 2048) {     // K -> hi/lo bf16 planes
#pragma unroll
        for (int i = 0; i < 4; i++)
#pragma unroll
            for (int j = 0; j < 4; j++) {
                int col = bn - 1024 + wn + j * 16 + l15;
#pragma unroll
                for (int r = 0; r < 4; r++) {
                    int row = bm + wm + i * 16 + quad * 4 + r;
                    u16 hh, ll;
                    split_hl(scrub(acc[i][j][r], 1e4f), hh, ll);
                    Kh[(size_t)row * 1024 + col] = hh;
                    Kl[(size_t)row * 1024 + col] = ll;
                }
            }
    } else {                    // V -> transposed bf16 vT[d][B*S]
#pragma unroll
        for (int i = 0; i < 4; i++)
#pragma unroll
            for (int j = 0; j < 4; j++) {
                int col = bn - 2048 + wn + j * 16 + l15;
                int row0 = bm + wm + i * 16 + quad * 4;
                ushort4 p;
                p.x = f2b(scrub(acc[i][j][0], 1e4f));
                p.y = f2b(scrub(acc[i][j][1], 1e4f));
                p.z = f2b(scrub(acc[i][j][2], 1e4f));
                p.w = f2b(scrub(acc[i][j][3], 1e4f));
                *(ushort4*)(vT + (size_t)col * 4096 + row0) = p;
            }
    }
}

// -------- GEMM: C fp32 = A bf16 [M,K] @ Bt [N,K]^T + Res fp32, BK=64 -------
__global__ __launch_bounds__(256) void gemm_bt_res(const u16* __restrict__ A,
                                                   const u16* __restrict__ Bt,
                                                   float* __restrict__ C,
                                                   const float* __restrict__ Res,
                                                   int M, int N, int K, float sval) {
    __shared__ __align__(16) u16 As[128 * 64];
    __shared__ __align__(16) u16 Bs[128 * 64];
    int tid = threadIdx.x;
    int wave = tid >> 6, lane = tid & 63, quad = lane >> 4, l15 = lane & 15;
    int bm = blockIdx.y * 128, bn = blockIdx.x * 128;
    int wm = (wave >> 1) * 64, wn = (wave & 1) * 64;
    f32x4 acc[4][4] = {};
    int lr = lane >> 3, cb = (lane & 7) ^ (lr & 7);
    const u16* ga = A + (size_t)(bm + wave * 32 + lr) * K + cb * 8;
    const u16* gb = Bt + (size_t)(bn + wave * 32 + lr) * K + cb * 8;
    u16* la = As + wave * 2048;
    u16* lb = Bs + wave * 2048;
    int swz = l15 & 7;
    for (int k0 = 0; k0 < K; k0 += 64) {
        __syncthreads();
#pragma unroll
        for (int g = 0; g < 4; g++) {
            gld16(ga + k0 + (size_t)(g * 8) * K, la + g * 512);
            gld16(gb + k0 + (size_t)(g * 8) * K, lb + g * 512);
        }
        __syncthreads();
#pragma unroll
        for (int s = 0; s < 2; s++) {
            int kb = ((s * 4 + quad) ^ swz) * 8;
            short8 af[4], bf[4];
#pragma unroll
            for (int i = 0; i < 4; i++)
                af[i] = ldf(As + (wm + i * 16 + l15) * 64 + kb);
#pragma unroll
            for (int j = 0; j < 4; j++)
                bf[j] = ldf(Bs + (wn + j * 16 + l15) * 64 + kb);
#pragma unroll
            for (int i = 0; i < 4; i++)
#pragma unroll
                for (int j = 0; j < 4; j++)
                    acc[i][j] = __builtin_amdgcn_mfma_f32_16x16x32_bf16(af[i], bf[j], acc[i][j], 0, 0, 0);
        }
    }
#pragma unroll
    for (int i = 0; i < 4; i++)
#pragma unroll
        for (int j = 0; j < 4; j++) {
            int col = bn + wn + j * 16 + l15;
#pragma unroll
            for (int r = 0; r < 4; r++) {
                int row = bm + wm + i * 16 + quad * 4 + r;
                float v = acc[i][j][r] + Res[(size_t)row * N + col];
                C[(size_t)row * N + col] = scrub(v, sval);
            }
        }
}

// -------- Dual GEMM + gated GELU v2: block 256x128, waves 128x64 -----------
// C = gelu(A@B1t^T) * (A@B2t^T), bf16 out. BK=64 XOR-swizzled staging.
// DS reads/MFMA = 0.25 (16 reads vs 128 MFMA per s-step pair) -> MFMA-bound.
__global__ __launch_bounds__(256) void gemm_dual_gelu(const u16* __restrict__ A,
                                                      const u16* __restrict__ B1t,
                                                      const u16* __restrict__ B2t,
                                                      u16* __restrict__ C,
                                                      int M, int N, int K) {
    __shared__ __align__(16) u16 As[256 * 64];   // 32 KB
    __shared__ __align__(16) u16 B1s[128 * 64];  // 16 KB
    __shared__ __align__(16) u16 B2s[128 * 64];  // 16 KB
    int tid = threadIdx.x;
    int wave = tid >> 6, lane = tid & 63, quad = lane >> 4, l15 = lane & 15;
    int bm = blockIdx.y * 256, bn = blockIdx.x * 128;
    int wm = (wave >> 1) * 128, wn = (wave & 1) * 64;
    f32x4 acc1[8][4] = {};
    f32x4 acc2[8][4] = {};
    int lr = lane >> 3, cb = (lane & 7) ^ (lr & 7);
    const u16* ga = A + (size_t)(bm + wave * 64 + lr) * K + cb * 8;
    const u16* g1 = B1t + (size_t)(bn + wave * 32 + lr) * K + cb * 8;
    const u16* g2 = B2t + (size_t)(bn + wave * 32 + lr) * K + cb * 8;
    u16* la = As + wave * 4096;   // 64 rows per wave
    u16* l1 = B1s + wave * 2048;  // 32 rows per wave
    u16* l2 = B2s + wave * 2048;
    int swz = l15 & 7;
    for (int k0 = 0; k0 < K; k0 += 64) {
        __syncthreads();
#pragma unroll
        for (int g = 0; g < 8; g++)
            gld16(ga + k0 + (size_t)(g * 8) * K, la + g * 512);
#pragma unroll
        for (int g = 0; g < 4; g++) {
            gld16(g1 + k0 + (size_t)(g * 8) * K, l1 + g * 512);
            gld16(g2 + k0 + (size_t)(g * 8) * K, l2 + g * 512);
        }
        __syncthreads();
#pragma unroll
        for (int s = 0; s < 2; s++) {
            int kb = ((s * 4 + quad) ^ swz) * 8;
            short8 b1f[4], b2f_[4];
#pragma unroll
            for (int j = 0; j < 4; j++) {
                b1f[j] = ldf(B1s + (wn + j * 16 + l15) * 64 + kb);
                b2f_[j] = ldf(B2s + (wn + j * 16 + l15) * 64 + kb);
            }
#pragma unroll
            for (int i = 0; i < 8; i++) {
                short8 af = ldf(As + (wm + i * 16 + l15) * 64 + kb);
#pragma unroll
                for (int j = 0; j < 4; j++) {
                    acc1[i][j] = __builtin_amdgcn_mfma_f32_16x16x32_bf16(af, b1f[j], acc1[i][j], 0, 0, 0);
                    acc2[i][j] = __builtin_amdgcn_mfma_f32_16x16x32_bf16(af, b2f_[j], acc2[i][j], 0, 0, 0);
                }
            }
        }
    }
#pragma unroll
    for (int i = 0; i < 8; i++)
#pragma unroll
        for (int j = 0; j < 4; j++) {
            int col = bn + wn + j * 16 + l15;
#pragma unroll
            for (int r = 0; r < 4; r++) {
                int row = bm + wm + i * 16 + quad * 4 + r;
                float v = gelu_new_f(acc1[i][j][r]) * acc2[i][j][r];
                C[(size_t)row * N + col] = f2b(scrub(v, 1e10f));
            }
        }
}

// -------- MFMA flash attention v4 ------------------------------------------
// grid (S/64, H, B), 256 thr. KT=64, Q A-frags direct from global, exp2
// softmax, MFMA row-sum denominator, XOR-swizzled K/V staging.
// T5 bucket saturation: for |rel| >= 91 the bias is constant per side, so
// tiles with |k0-q0| >= 192 (block-uniform!) skip the 16 table gathers/iter.
__global__ __launch_bounds__(256) void attn_kernel(const float* __restrict__ Qb,
                                                   const u16* __restrict__ Kh,
                                                   const u16* __restrict__ Kl,
                                                   const u16* __restrict__ vT,
                                                   const float* __restrict__ bias_tab,
                                                   const float* __restrict__ mask_add,
                                                   u16* __restrict__ Ctx) {
    __shared__ __align__(16) u16 Khs[64 * 64];  // swizzled: blk ^= (row&7)
    __shared__ __align__(16) u16 Kls[64 * 64];
    __shared__ __align__(16) u16 Vs[64 * 64];   // [d][kv], swizzled
    __shared__ __align__(16) u16 Pss[4 * 16 * 72];
    const float LOG2E = 1.4426950408889634f;
    int tid = threadIdx.x, wave = tid >> 6, lane = tid & 63;
    int quad = lane >> 4, l15 = lane & 15;
    int h = blockIdx.y, b = blockIdx.z;
    int q0 = blockIdx.x * 64;
    // Q A-fragment direct load: lane owns q-row (wave*16+l15), k = half*32+quad*8+j
    short8 qh0, qh1, ql0, ql1;
    {
        const float* Qg = Qb + (size_t)(b * 2048 + q0 + wave * 16 + l15) * 1024 + h * 64 + quad * 8;
#pragma unroll
        for (int half = 0; half < 2; half++) {
            float4 a = *(const float4*)(Qg + half * 32);
            float4 c = *(const float4*)(Qg + half * 32 + 4);
            u16 hh, ll;
            float vals[8] = {a.x, a.y, a.z, a.w, c.x, c.y, c.z, c.w};
#pragma unroll
            for (int j = 0; j < 8; j++) {
                split_hl(vals[j] * LOG2E, hh, ll);
                if (half == 0) { qh0[j] = (short)hh; ql0[j] = (short)ll; }
                else           { qh1[j] = (short)hh; ql1[j] = (short)ll; }
            }
        }
    }
    f32x4 O[4] = {};
    f32x4 O4 = {};   // row-sums of P via ones-MFMA -> softmax denominator
    short8 vones;
#pragma unroll
    for (int i = 0; i < 8; i++) vones[i] = (short)0x3f80; // bf16 1.0
    u16* Pw = Pss + wave * 16 * 72;
    int my_q = q0 + wave * 16 + quad * 4;
    const float* bt = bias_tab + h * 4096;
    const float* ma = mask_add + b * 2048;
    float bsat_neg = bt[0];      // bias for rel <= -91 (saturated)
    float bsat_pos = bt[4094];   // bias for rel >= +91 (saturated)
    // swizzled staging: wave w fills rows [w*16, w*16+16)
    int lr8 = lane >> 3, cb = (lane & 7) ^ (lr8 & 7);
    const u16* gkh = Kh + (size_t)(b * 2048 + wave * 16 + lr8) * 1024 + h * 64 + cb * 8;
    const u16* gkl = Kl + (size_t)(b * 2048 + wave * 16 + lr8) * 1024 + h * 64 + cb * 8;
    const u16* gv  = vT + (size_t)(h * 64 + wave * 16 + lr8) * 4096 + b * 2048 + cb * 8;
    u16* lkh = Khs + wave * 1024;
    u16* lkl = Kls + wave * 1024;
    u16* lv  = Vs + wave * 1024;
    int sw = l15 & 7;
    int swK0 = (quad ^ sw) * 8, swK1 = ((quad + 4) ^ sw) * 8;

    for (int k0 = 0; k0 < 2048; k0 += 64) {
        __syncthreads();
        gld16(gkh + (size_t)k0 * 1024, lkh);
        gld16(gkh + (size_t)k0 * 1024 + 8 * 1024, lkh + 512);
        gld16(gkl + (size_t)k0 * 1024, lkl);
        gld16(gkl + (size_t)k0 * 1024 + 8 * 1024, lkl + 512);
        gld16(gv + k0, lv);
        gld16(gv + k0 + (size_t)8 * 4096, lv + 512);
        __syncthreads();
        float pv[4][4];
        int dq = k0 - q0;
        if (dq >= 192 || dq <= -192) {
            // saturated-bias fast path: additive term is r-independent
            float bsat = dq > 0 ? bsat_pos : bsat_neg;
#pragma unroll
            for (int t = 0; t < 4; t++) {
                const u16* krow = Khs + (t * 16 + l15) * 64;
                const u16* lrow = Kls + (t * 16 + l15) * 64;
                short8 kh0 = ldf(krow + swK0);
                short8 kh1 = ldf(krow + swK1);
                short8 kl0 = ldf(lrow + swK0);
                short8 kl1 = ldf(lrow + swK1);
                f32x4 z = {0.0f, 0.0f, 0.0f, 0.0f};
                z = __builtin_amdgcn_mfma_f32_16x16x32_bf16(ql0, kh0, z, 0, 0, 0);
                z = __builtin_amdgcn_mfma_f32_16x16x32_bf16(ql1, kh1, z, 0, 0, 0);
                z = __builtin_amdgcn_mfma_f32_16x16x32_bf16(qh0, kl0, z, 0, 0, 0);
                z = __builtin_amdgcn_mfma_f32_16x16x32_bf16(qh1, kl1, z, 0, 0, 0);
                z = __builtin_amdgcn_mfma_f32_16x16x32_bf16(qh0, kh0, z, 0, 0, 0);
                z = __builtin_amdgcn_mfma_f32_16x16x32_bf16(qh1, kh1, z, 0, 0, 0);
                float c = ma[k0 + t * 16 + l15] + bsat;
#pragma unroll
                for (int r = 0; r < 4; r++)
                    pv[t][r] = exp2f(z[r] + c);
            }
        } else {
            // diagonal tiles: per-element bucket table gather
#pragma unroll
            for (int t = 0; t < 4; t++) {
                const u16* krow = Khs + (t * 16 + l15) * 64;
                const u16* lrow = Kls + (t * 16 + l15) * 64;
                short8 kh0 = ldf(krow + swK0);
                short8 kh1 = ldf(krow + swK1);
                short8 kl0 = ldf(lrow + swK0);
                short8 kl1 = ldf(lrow + swK1);
                f32x4 z = {0.0f, 0.0f, 0.0f, 0.0f};
                z = __builtin_amdgcn_mfma_f32_16x16x32_bf16(ql0, kh0, z, 0, 0, 0);
                z = __builtin_amdgcn_mfma_f32_16x16x32_bf16(ql1, kh1, z, 0, 0, 0);
                z = __builtin_amdgcn_mfma_f32_16x16x32_bf16(qh0, kl0, z, 0, 0, 0);
                z = __builtin_amdgcn_mfma_f32_16x16x32_bf16(qh1, kl1, z, 0, 0, 0);
                z = __builtin_amdgcn_mfma_f32_16x16x32_bf16(qh0, kh0, z, 0, 0, 0);
                z = __builtin_amdgcn_mfma_f32_16x16x32_bf16(qh1, kh1, z, 0, 0, 0);
                int kcol = k0 + t * 16 + l15;
                float madd = ma[kcol];
#pragma unroll
                for (int r = 0; r < 4; r++)
                    pv[t][r] = exp2f(z[r] + bt[kcol - (my_q + r) + 2047] + madd);
            }
        }
#pragma unroll
        for (int t = 0; t < 4; t++)
#pragma unroll
            for (int r = 0; r < 4; r++)
                Pw[(quad * 4 + r) * 72 + t * 16 + l15] = f2b(pv[t][r]);
#pragma unroll
        for (int h2 = 0; h2 < 2; h2++) {
            short8 pf = ldf(Pw + l15 * 72 + h2 * 32 + quad * 8);
#pragma unroll
            for (int nt = 0; nt < 4; nt++) {
                short8 vf = ldf(Vs + (nt * 16 + l15) * 64 + ((h2 * 4 + quad) ^ sw) * 8);
                O[nt] = __builtin_amdgcn_mfma_f32_16x16x32_bf16(pf, vf, O[nt], 0, 0, 0);
            }
            O4 = __builtin_amdgcn_mfma_f32_16x16x32_bf16(pf, vones, O4, 0, 0, 0);
        }
    }
    u16* Cg = Ctx + ((size_t)(b * 2048 + my_q)) * 1024 + h * 64;
#pragma unroll
    for (int nt = 0; nt < 4; nt++)
#pragma unroll
        for (int r = 0; r < 4; r++) {
            float v = O[nt][r] / fmaxf(O4[r], 1e-30f);
            Cg[(size_t)r * 1024 + nt * 16 + l15] = f2b(scrub(v, 1e6f));
        }
}

// ---------------------------------------------------------------------------
extern "C" void kernel_launch(void* const* d_in, const int* in_sizes, int n_in,
                              void* d_out, int out_size, void* d_ws, size_t ws_size,
                              hipStream_t stream) {
    const float* hidden = (const float*)d_in[0];
    const float* mask   = (const float*)d_in[1];
    const float* ln1_w  = (const float*)d_in[2];
    const float* wq     = (const float*)d_in[3];
    const float* wk     = (const float*)d_in[4];
    const float* wv     = (const float*)d_in[5];
    const float* relb   = (const float*)d_in[6];
    const float* wo     = (const float*)d_in[7];
    const float* ln2_w  = (const float*)d_in[8];
    const float* w1     = (const float*)d_in[9];
    const float* w2     = (const float*)d_in[10];
    const float* w_out  = (const float*)d_in[11];
    float* out = (float*)d_out;

    // workspace layout (MB), phase-multiplexed (peak ~64.3 MB):
    //  0- 6 : qkvT            -> woutT (0-8, after out-proj)
    //  6- 8 : woT
    //  8-16 : w1T   16-24 : w2T
    // 24-32 : normed -> ctx -> normed2
    // 32-40 : (free)   \
    // 40-48 : Kh         \ ffg (32-64, FFN phase)
    // 48-56 : Kl         /
    // 56-64 : vT       /
    // 64-   : bias_tab (256K) + mask_add (16K)
    // Q (fp32) lives in d_out until out-proj overwrites it with the trunk.
    char* w = (char*)d_ws;
    const size_t MB = 1u << 20;
    u16*   qkvT    = (u16*)(w + 0 * MB);
    u16*   woutT   = (u16*)(w + 0 * MB);
    u16*   woT     = (u16*)(w + 6 * MB);
    u16*   w1T     = (u16*)(w + 8 * MB);
    u16*   w2T     = (u16*)(w + 16 * MB);
    u16*   normed  = (u16*)(w + 24 * MB);
    u16*   ctx     = (u16*)(w + 24 * MB);
    u16*   normed2 = (u16*)(w + 24 * MB);
    u16*   Kh      = (u16*)(w + 40 * MB);
    u16*   Kl      = (u16*)(w + 48 * MB);
    u16*   vT      = (u16*)(w + 56 * MB);
    u16*   ffg     = (u16*)(w + 32 * MB);
    float* bias_tab = (float*)(w + 64 * MB);
    float* mask_add = (float*)(w + 64 * MB + 256 * 1024);
    float* qb      = (float*)d_out;

    dim3 blk(256);
    // weight transposes fp32 -> bf16 [N][K]; wq/wk/wv into one qkvT [3072][1024]
    transpose_cvt<<<dim3(32, 32), blk, 0, stream>>>(wq, qkvT, 1024, 1024);
    transpose_cvt<<<dim3(32, 32), blk, 0, stream>>>(wk, qkvT + 1024 * 1024, 1024, 1024);
    transpose_cvt<<<dim3(32, 32), blk, 0, stream>>>(wv, qkvT + 2048 * 1024, 1024, 1024);
    transpose_cvt<<<dim3(32, 32), blk, 0, stream>>>(wo, woT, 1024, 1024);
    transpose_cvt<<<dim3(128, 32), blk, 0, stream>>>(w1, w1T, 1024, 4096);
    transpose_cvt<<<dim3(128, 32), blk, 0, stream>>>(w2, w2T, 1024, 4096);
    bias_table_kernel<<<16, 256, 0, stream>>>(relb, mask, bias_tab, mask_add);

    // pre-LN 1 + merged QKV projection (single-plane A)
    rmsnorm_k<<<4096, blk, 0, stream>>>(hidden, ln1_w, normed);
    gemm_qkv<<<dim3(24, 32), blk, 0, stream>>>(normed, qkvT, qb, Kh, Kl, vT);

    // attention (ctx overwrites dead normed region)
    attn_kernel<<<dim3(32, 16, 2), blk, 0, stream>>>(qb, Kh, Kl, vT, bias_tab, mask_add, ctx);

    // output proj + residual -> fp32 trunk in d_out (overwrites qb)
    gemm_bt_res<<<dim3(8, 32), blk, 0, stream>>>(ctx, woT, out, hidden, 4096, 1024, 1024, 1e8f);

    // transpose w_out into now-dead qkvT/woT region
    transpose_cvt<<<dim3(32, 128), blk, 0, stream>>>(w_out, woutT, 4096, 1024);

    // pre-LN 2 + gated FFN + final residual
    rmsnorm_k<<<4096, blk, 0, stream>>>(out, ln2_w, normed2);
    gemm_dual_gelu<<<dim3(32, 16), blk, 0, stream>>>(normed2, w1T, w2T, ffg, 4096, 4096, 1024);
    gemm_bt_res<<<dim3(8, 32), blk, 0, stream>>>(ffg, woutT, out, out, 4096, 1024, 4096, 1e12f);
}